// Round 4
// baseline (534.958 us; speedup 1.0000x reference)
//
#include <hip/hip_runtime.h>

// Problem constants
#define NB   4      // batch
#define NN   4      // contexts per pixel
#define CCh  256    // Cc
#define CFh  512    // Cf
#define HH   128
#define WW   128
#define PLO  4096   // 64*64 low-res pixels
#define PHI  16384  // 128*128 hi-res pixels

typedef __bf16 bf16;
typedef __bf16 bf16x8 __attribute__((ext_vector_type(8)));
typedef float  f32x4  __attribute__((ext_vector_type(4)));
typedef float  f32x2  __attribute__((ext_vector_type(2)));

__device__ __forceinline__ void gll16(const void* g, void* lds) {
    __builtin_amdgcn_global_load_lds(
        (const __attribute__((address_space(1))) void*)g,
        (__attribute__((address_space(3))) void*)lds, 16, 0, 0);
}

__device__ __forceinline__ unsigned pack2bf(float a, float b) {
    unsigned short ua = __builtin_bit_cast(unsigned short, (bf16)a);
    unsigned short ub = __builtin_bit_cast(unsigned short, (bf16)b);
    return (unsigned)ua | ((unsigned)ub << 16);
}

// ---------------------------------------------------------------------------
// prep 1: M_qk[c][f] = sum_o Wc_w[o][c] * Wf_w[o][f]  (bf16 out)
//         d_qk[c]    = sum_o Wc_w[o][c] * Wf_b[o]     (fp32, parallel reduce)
__global__ void prep_mqk(const float* __restrict__ Wc_w, const float* __restrict__ Wf_w,
                         const float* __restrict__ Wf_b, bf16* __restrict__ M_qk,
                         float* __restrict__ d_qk) {
    __shared__ float red[256];
    int c = blockIdx.y;
    int f = blockIdx.x * 256 + threadIdx.x;
    float s = 0.f;
#pragma unroll 8
    for (int o = 0; o < CCh; ++o)
        s += Wc_w[o * CCh + c] * Wf_w[o * CFh + f];
    M_qk[c * CFh + f] = (bf16)s;
    if (blockIdx.x == 0) {          // block-uniform branch: barriers are safe
        int o = threadIdx.x;
        red[o] = Wc_w[o * CCh + c] * Wf_b[o];
        __syncthreads();
        for (int st = 128; st > 0; st >>= 1) {
            if (threadIdx.x < st) red[threadIdx.x] += red[threadIdx.x + st];
            __syncthreads();
        }
        if (threadIdx.x == 0) d_qk[c] = red[0];
    }
}

// ---------------------------------------------------------------------------
// prep 2: transpose mainstream [B][512][4096] fp32 -> ms_t [B][4096][512] bf16
// Write phase packs 2 bf16 per u32 store (halves store instrs vs scalar bf16).
__global__ void prep_ms(const float* __restrict__ ms, bf16* __restrict__ ms_t) {
    __shared__ float tile[32][33];   // [f_local][p_local]
    int b = blockIdx.z;
    int p0 = blockIdx.x * 32, f0 = blockIdx.y * 32;
    int tx = threadIdx.x;
    int r = tx >> 5, cc = tx & 31;
    const float* src = ms + (size_t)b * CFh * PLO;
#pragma unroll
    for (int q = 0; q < 4; ++q) {
        int fl = q * 8 + r;
        tile[fl][cc] = src[(size_t)(f0 + fl) * PLO + p0 + cc];
    }
    __syncthreads();
    bf16* dst = ms_t + (size_t)b * PLO * CFh;
    int fp = tx & 15;                // f-pair index: f_local = 2*fp, 2*fp+1
    int r2 = tx >> 4;                // 0..15
#pragma unroll
    for (int q = 0; q < 2; ++q) {
        int pl = q * 16 + r2;        // p_local 0..31
        unsigned w = pack2bf(tile[2 * fp][pl], tile[2 * fp + 1][pl]);
        *((unsigned*)(dst + (size_t)(p0 + pl) * CFh + f0) + fp) = w;
    }
}

// ---------------------------------------------------------------------------
// prep 3: pack Wv_w [256][512][3][3] fp32 -> Wv_p [9][256][512] bf16; zero zerobuf
__global__ void prep_wv(const float* __restrict__ Wv_w, bf16* __restrict__ Wv_p,
                        bf16* __restrict__ zerob) {
    int tid = blockIdx.x * 256 + threadIdx.x;   // t-major: (t*256 + c)*512 + f
    int t = tid / (CCh * CFh);
    int rem = tid % (CCh * CFh);
    int c = rem / CFh, f = rem % CFh;
    Wv_p[tid] = (bf16)Wv_w[(size_t)(c * CFh + f) * 9 + t];
    if (tid < 1024) zerob[tid] = (bf16)0.f;
}

// ---------------------------------------------------------------------------
// GEMM: M=channels(128-tile), N=pixels(128-tile), BK=32, 256 thr = 4 waves.
// grid (32, 2, 16): z<12 -> conv tap-group tg=z%3, b=z/3, taps [3tg,3tg+3),
//   writes fp32 partials (no bias) to v3[tg][b][256][4096].
// z>=12 -> qk (1 tap), b=z-12, writes bf16 (+d_qk bias) to qk_out.
// (R0-proven structure: serial stage, compiler-scheduled, 4 blocks/CU.)
__global__ __launch_bounds__(256) void gemm_kernel(
    const bf16* __restrict__ Wv_p,   // [9][256][512]
    const bf16* __restrict__ M_qk,   // [256][512]
    const bf16* __restrict__ ms_t,   // [B][4096][512]
    const float* __restrict__ d_qk,
    const bf16* __restrict__ zerob,
    float* __restrict__ v3, bf16* __restrict__ qk_out) {
    __shared__ __align__(16) bf16 Alds[128 * 32];  // [c][f]
    __shared__ __align__(16) bf16 Blds[128 * 32];  // [p][f]

    const int tx = threadIdx.x;
    const int wave = tx >> 6, lane = tx & 63;
    const int ptile = blockIdx.x, ctile = blockIdx.y;
    const int z = blockIdx.z;
    const int mode = (z >= 12);                 // 0=conv partial, 1=qk
    const int b = mode ? (z - 12) : (z / 3);
    const int tg = mode ? 0 : (z % 3);
    const int t0 = tg * 3;
    const int ntaps = mode ? 1 : 3;

    const bf16* Wbase = mode ? M_qk : (Wv_p + (size_t)t0 * CCh * CFh);
    const bf16* msb = ms_t + (size_t)b * PLO * CFh;

    // staging lane mapping: issue q covers bytes [wave*2048 + q*1024, +1024)
    int idx0 = wave * 2048 + lane * 16;
    int idx1 = idx0 + 1024;
    int rA0 = idx0 >> 6, fq0 = (idx0 >> 4) & 3;   // row 0..127, 16B-chunk 0..3
    int rA1 = idx1 >> 6, fq1 = (idx1 >> 4) & 3;
    const size_t aoff0 = (size_t)(ctile * 128 + rA0) * CFh + fq0 * 8;
    const size_t aoff1 = (size_t)(ctile * 128 + rA1) * CFh + fq1 * 8;
    char* ldsA0 = (char*)Alds + wave * 2048;
    char* ldsA1 = ldsA0 + 1024;
    char* ldsB0 = (char*)Blds + wave * 2048;
    char* ldsB1 = ldsB0 + 1024;

    const int p0 = ptile * 128 + rA0, p1 = ptile * 128 + rA1;
    const int i0 = p0 >> 6, j0 = p0 & 63;
    const int i1 = p1 >> 6, j1 = p1 & 63;

    f32x4 acc[4][4];
#pragma unroll
    for (int mi = 0; mi < 4; ++mi)
#pragma unroll
        for (int ni = 0; ni < 4; ++ni) acc[mi][ni] = f32x4{0.f, 0.f, 0.f, 0.f};

    const int wm = wave >> 1, wn = wave & 1;
    const int quad = lane >> 4, l15 = lane & 15;

    for (int t = 0; t < ntaps; ++t) {
        const int dy = mode ? 0 : ((t0 + t) / 3 - 1);
        const int dx = mode ? 0 : ((t0 + t) % 3 - 1);
        const bf16* Wt = Wbase + (size_t)t * CCh * CFh;
        int si0 = i0 + dy, sj0 = j0 + dx, si1 = i1 + dy, sj1 = j1 + dx;
        bool ok0 = (unsigned)si0 < 64u && (unsigned)sj0 < 64u;
        bool ok1 = (unsigned)si1 < 64u && (unsigned)sj1 < 64u;
        const bf16* bsrc0 = ok0 ? msb + (size_t)(si0 * 64 + sj0) * CFh + fq0 * 8 : zerob;
        const bf16* bsrc1 = ok1 ? msb + (size_t)(si1 * 64 + sj1) * CFh + fq1 * 8 : zerob;

        for (int fc = 0; fc < CFh / 32; ++fc) {
            const int f0 = fc * 32;
            __syncthreads();   // prev compute done before overwriting LDS
            gll16(Wt + aoff0 + f0, ldsA0);
            gll16(Wt + aoff1 + f0, ldsA1);
            gll16(bsrc0 + f0, ldsB0);
            gll16(bsrc1 + f0, ldsB1);
            __syncthreads();

            bf16x8 af[4], bfr[4];
#pragma unroll
            for (int mi = 0; mi < 4; ++mi)
                af[mi] = *(const bf16x8*)&Alds[(wm * 64 + mi * 16 + l15) * 32 + quad * 8];
#pragma unroll
            for (int ni = 0; ni < 4; ++ni)
                bfr[ni] = *(const bf16x8*)&Blds[(wn * 64 + ni * 16 + l15) * 32 + quad * 8];
#pragma unroll
            for (int mi = 0; mi < 4; ++mi)
#pragma unroll
                for (int ni = 0; ni < 4; ++ni)
                    acc[mi][ni] = __builtin_amdgcn_mfma_f32_16x16x32_bf16(
                        af[mi], bfr[ni], acc[mi][ni], 0, 0, 0);
        }
    }

    // C/D layout: col = lane&15 (pixel), row = quad*4 + r (channel)
    if (mode) {
        bf16* obase = qk_out + (size_t)b * CCh * PLO;
#pragma unroll
        for (int mi = 0; mi < 4; ++mi) {
            int cb = ctile * 128 + wm * 64 + mi * 16 + quad * 4;
#pragma unroll
            for (int ni = 0; ni < 4; ++ni) {
                int p = ptile * 128 + wn * 64 + ni * 16 + l15;
                bf16* op = obase + (size_t)cb * PLO + p;
#pragma unroll
                for (int r = 0; r < 4; ++r)
                    op[(size_t)r * PLO] = (bf16)(acc[mi][ni][r] + d_qk[cb + r]);
            }
        }
    } else {
        float* obase = v3 + (size_t)(tg * NB + b) * CCh * PLO;
#pragma unroll
        for (int mi = 0; mi < 4; ++mi) {
            int cb = ctile * 128 + wm * 64 + mi * 16 + quad * 4;
#pragma unroll
            for (int ni = 0; ni < 4; ++ni) {
                int p = ptile * 128 + wn * 64 + ni * 16 + l15;
                float* op = obase + (size_t)cb * PLO + p;
#pragma unroll
                for (int r = 0; r < 4; ++r)
                    op[(size_t)r * PLO] = acc[mi][ni][r];
            }
        }
    }
}

// ---------------------------------------------------------------------------
// attention: block = 512 thr, 64 pixels (one 64-wide w strip).
// NO register caching of ctx: phase 1 streams ctx for scores; phase 3 re-reads
// ctx (L3-hit: same block, ~µs gap; device in-flight set ~128MB < 256MB L3).
// Base pointer laundered through inline asm between phases to defeat load CSE
// (else compiler re-materializes the 128-VGPR vals cache).
// Target: VGPR <= ~100 -> 4-5 waves/SIMD (vs 2 with vals cache).
__global__ __launch_bounds__(512) void attn_kernel(
    const float* __restrict__ ctx,   // [4][4][256][128][128]
    const bf16* __restrict__ qk,     // [4][256][4096]
    const float* __restrict__ v3,    // [3][4][256][4096] conv partials
    const float* __restrict__ Wv_b,  // [256]
    float* __restrict__ out) {       // [4][256][128][128]
    __shared__ f32x4 swred[4][8][16];  // [n][wave][pq]
    const int tx = threadIdx.x;
    const int pq = tx & 15;            // which 4-pixel group
    const int cc = tx >> 4;            // channel chunk 0..31
    const int lane = tx & 63;
    const int wv = tx >> 6;
    const int quad = lane >> 4;

    const int pbase = blockIdx.x << 6;
    const int b = pbase >> 14;
    const int rem = pbase & 16383;
    const int hh = rem >> 7;
    const int w0 = rem & 127;          // 0 or 64
    const int wq = w0 + pq * 4;
    const int i = hh >> 1, j0 = wq >> 1;   // j0 even

    const int c0 = cc * 8;
    const size_t NSTR = (size_t)CCh * PHI;
    const float* cbase = ctx + (size_t)b * NN * NSTR + (size_t)c0 * PHI
                             + (size_t)hh * WW + wq;
    const bf16* qkb = qk + ((size_t)b * CCh + c0) * PLO + i * 64 + j0;
    const float* vbp = v3 + ((size_t)b * CCh + c0) * PLO + i * 64 + j0;

    f32x4 s[4];
#pragma unroll
    for (int n = 0; n < 4; ++n) s[n] = f32x4{0.f, 0.f, 0.f, 0.f};

    // phase 1: stream ctx, accumulate scores (loads NOT retained)
#pragma unroll
    for (int cj = 0; cj < 8; ++cj) {
        unsigned qw = *(const unsigned*)(qkb + (size_t)cj * PLO);
        float qa = __uint_as_float(qw << 16);
        float qb = __uint_as_float(qw & 0xffff0000u);
        f32x4 qv = {qa, qa, qb, qb};
#pragma unroll
        for (int n = 0; n < 4; ++n)
            s[n] += *(const f32x4*)(cbase + n * NSTR + (size_t)cj * PHI) * qv;
    }

    // launder the ctx base pointer: compiler must not CSE phase-3 reloads
    // against phase-1 loads (that would re-create the 128-VGPR live cache).
    const float* cbase2 = cbase;
    asm volatile("" : "+v"(cbase2));

    // reduce over the 4 quads within each wave (cc bits 0..1 live in lane bits 4..5)
#pragma unroll
    for (int n = 0; n < 4; ++n) {
#pragma unroll
        for (int m = 16; m <= 32; m <<= 1) {
            f32x4 t;
            t[0] = __shfl_xor(s[n][0], m);
            t[1] = __shfl_xor(s[n][1], m);
            t[2] = __shfl_xor(s[n][2], m);
            t[3] = __shfl_xor(s[n][3], m);
            s[n] += t;
        }
    }
    // lane with quad q publishes n=q for its wave
    f32x4 sq = (quad == 0) ? s[0] : (quad == 1) ? s[1] : (quad == 2) ? s[2] : s[3];
    swred[quad][wv][pq] = sq;
    __syncthreads();

    f32x4 t4[4];
#pragma unroll
    for (int n = 0; n < 4; ++n) {
        f32x4 a = swred[n][0][pq];
#pragma unroll
        for (int w = 1; w < 8; ++w) a += swred[n][w][pq];
        t4[n] = a;
    }
    f32x4 mx;
#pragma unroll
    for (int k = 0; k < 4; ++k)
        mx[k] = fmaxf(fmaxf(t4[0][k], t4[1][k]), fmaxf(t4[2][k], t4[3][k]));
    f32x4 e[4];
#pragma unroll
    for (int n = 0; n < 4; ++n)
#pragma unroll
        for (int k = 0; k < 4; ++k) e[n][k] = __expf(t4[n][k] - mx[k]);
    f32x4 ssum = e[0] + e[1] + e[2] + e[3];
    f32x4 a4[4];
#pragma unroll
    for (int n = 0; n < 4; ++n)
#pragma unroll
        for (int k = 0; k < 4; ++k) a4[n][k] = e[n][k] / ssum[k];

    // phase 3: re-read ctx (L3-hot), weighted sum + conv partials + bias
    float* outp = out + ((size_t)b * CCh + c0) * PHI + (size_t)hh * WW + wq;
#pragma unroll
    for (int cj = 0; cj < 8; ++cj) {
        f32x2 vv = *(const f32x2*)(vbp + (size_t)cj * PLO);
        vv += *(const f32x2*)(vbp + 4194304 + (size_t)cj * PLO);
        vv += *(const f32x2*)(vbp + 8388608 + (size_t)cj * PLO);
        float bc = Wv_b[c0 + cj];
        float va = vv[0] + bc, vb2 = vv[1] + bc;
        f32x4 o = f32x4{va, va, vb2, vb2};
#pragma unroll
        for (int n = 0; n < 4; ++n)
            o += *(const f32x4*)(cbase2 + n * NSTR + (size_t)cj * PHI) * a4[n];
        *(f32x4*)(outp + (size_t)cj * PHI) = o;
    }
}

// ---------------------------------------------------------------------------
extern "C" void kernel_launch(void* const* d_in, const int* in_sizes, int n_in,
                              void* d_out, int out_size, void* d_ws, size_t ws_size,
                              hipStream_t stream) {
    const float* ctx  = (const float*)d_in[0];
    const float* ms   = (const float*)d_in[1];
    const float* Wc_w = (const float*)d_in[2];
    // d_in[3] = Wc_b: constant across n at each pixel -> cancels in softmax.
    const float* Wf_w = (const float*)d_in[4];
    const float* Wf_b = (const float*)d_in[5];
    const float* Wv_w = (const float*)d_in[6];
    const float* Wv_b = (const float*)d_in[7];
    float* out = (float*)d_out;

    char* ws = (char*)d_ws;
    bf16*  ms_t  = (bf16*)ws;                     // 16,777,216 B
    bf16*  Wv_p  = (bf16*)(ws + 16777216);        //  2,359,296 B
    bf16*  M_qk  = (bf16*)(ws + 19136512);        //    262,144 B
    float* d_qk  = (float*)(ws + 19398656);       //      1,024 B
    bf16*  zerob = (bf16*)(ws + 19399680);        //      2,048 B
    bf16*  qk    = (bf16*)(ws + 19401728);        //  8,388,608 B
    float* v3    = (float*)(ws + 27790336);       // 50,331,648 B (total ~78.1 MB)

    prep_mqk<<<dim3(2, 256), 256, 0, stream>>>(Wc_w, Wf_w, Wf_b, M_qk, d_qk);
    prep_ms<<<dim3(128, 16, 4), 256, 0, stream>>>(ms, ms_t);
    prep_wv<<<dim3(4608), 256, 0, stream>>>(Wv_w, Wv_p, zerob);
    gemm_kernel<<<dim3(32, 2, 16), 256, 0, stream>>>(Wv_p, M_qk, ms_t, d_qk,
                                                     zerob, v3, qk);
    attn_kernel<<<dim3(1024), 512, 0, stream>>>(ctx, qk, v3, Wv_b, out);
}

// Round 5
// 513.654 us; speedup vs baseline: 1.0415x; 1.0415x over previous
//
#include <hip/hip_runtime.h>

// Problem constants
#define NB   4      // batch
#define NN   4      // contexts per pixel
#define CCh  256    // Cc
#define CFh  512    // Cf
#define HH   128
#define WW   128
#define PLO  4096   // 64*64 low-res pixels
#define PHI  16384  // 128*128 hi-res pixels

typedef __bf16 bf16;
typedef __bf16 bf16x8 __attribute__((ext_vector_type(8)));
typedef float  f32x4  __attribute__((ext_vector_type(4)));
typedef float  f32x2  __attribute__((ext_vector_type(2)));

__device__ __forceinline__ void gll16(const void* g, void* lds) {
    __builtin_amdgcn_global_load_lds(
        (const __attribute__((address_space(1))) void*)g,
        (__attribute__((address_space(3))) void*)lds, 16, 0, 0);
}

__device__ __forceinline__ unsigned pack2bf(float a, float b) {
    unsigned short ua = __builtin_bit_cast(unsigned short, (bf16)a);
    unsigned short ub = __builtin_bit_cast(unsigned short, (bf16)b);
    return (unsigned)ua | ((unsigned)ub << 16);
}

// ---------------------------------------------------------------------------
// prep 1: M_qk[c][f] = sum_o Wc_w[o][c] * Wf_w[o][f]  (bf16 out)
//         d_qk[c]    = sum_o Wc_w[o][c] * Wf_b[o]     (fp32, parallel reduce)
__global__ void prep_mqk(const float* __restrict__ Wc_w, const float* __restrict__ Wf_w,
                         const float* __restrict__ Wf_b, bf16* __restrict__ M_qk,
                         float* __restrict__ d_qk) {
    __shared__ float red[256];
    int c = blockIdx.y;
    int f = blockIdx.x * 256 + threadIdx.x;
    float s = 0.f;
#pragma unroll 8
    for (int o = 0; o < CCh; ++o)
        s += Wc_w[o * CCh + c] * Wf_w[o * CFh + f];
    M_qk[c * CFh + f] = (bf16)s;
    if (blockIdx.x == 0) {          // block-uniform branch: barriers are safe
        int o = threadIdx.x;
        red[o] = Wc_w[o * CCh + c] * Wf_b[o];
        __syncthreads();
        for (int st = 128; st > 0; st >>= 1) {
            if (threadIdx.x < st) red[threadIdx.x] += red[threadIdx.x + st];
            __syncthreads();
        }
        if (threadIdx.x == 0) d_qk[c] = red[0];
    }
}

// ---------------------------------------------------------------------------
// prep 2: transpose mainstream [B][512][4096] fp32 -> ms_t [B][4096][512] bf16
// Write phase packs 2 bf16 per u32 store (halves store instrs vs scalar bf16).
__global__ void prep_ms(const float* __restrict__ ms, bf16* __restrict__ ms_t) {
    __shared__ float tile[32][33];   // [f_local][p_local]
    int b = blockIdx.z;
    int p0 = blockIdx.x * 32, f0 = blockIdx.y * 32;
    int tx = threadIdx.x;
    int r = tx >> 5, cc = tx & 31;
    const float* src = ms + (size_t)b * CFh * PLO;
#pragma unroll
    for (int q = 0; q < 4; ++q) {
        int fl = q * 8 + r;
        tile[fl][cc] = src[(size_t)(f0 + fl) * PLO + p0 + cc];
    }
    __syncthreads();
    bf16* dst = ms_t + (size_t)b * PLO * CFh;
    int fp = tx & 15;                // f-pair index: f_local = 2*fp, 2*fp+1
    int r2 = tx >> 4;                // 0..15
#pragma unroll
    for (int q = 0; q < 2; ++q) {
        int pl = q * 16 + r2;        // p_local 0..31
        unsigned w = pack2bf(tile[2 * fp][pl], tile[2 * fp + 1][pl]);
        *((unsigned*)(dst + (size_t)(p0 + pl) * CFh + f0) + fp) = w;
    }
}

// ---------------------------------------------------------------------------
// prep 3: pack Wv_w [256][512][3][3] fp32 -> Wv_p [9][256][512] bf16; zero zerobuf
__global__ void prep_wv(const float* __restrict__ Wv_w, bf16* __restrict__ Wv_p,
                        bf16* __restrict__ zerob) {
    int tid = blockIdx.x * 256 + threadIdx.x;   // t-major: (t*256 + c)*512 + f
    int t = tid / (CCh * CFh);
    int rem = tid % (CCh * CFh);
    int c = rem / CFh, f = rem % CFh;
    Wv_p[tid] = (bf16)Wv_w[(size_t)(c * CFh + f) * 9 + t];
    if (tid < 1024) zerob[tid] = (bf16)0.f;
}

// ---------------------------------------------------------------------------
// GEMM: M=channels(128-tile), N=pixels(128-tile), BK=32, 256 thr = 4 waves.
// grid (32, 2, 16): z<12 -> conv tap-group tg=z%3, b=z/3, taps [3tg,3tg+3),
//   writes fp32 partials (no bias) to v3[tg][b][256][4096].
// z>=12 -> qk (1 tap), b=z-12, writes bf16 (+d_qk bias) to qk_out.
// R0 macro-structure (grid/tap-split/staging-map) + T4 pipeline: double-buffered
// LDS, counted s_waitcnt vmcnt(4) (never 0 in-loop), raw s_barrier. Loads for
// K-step it+1 are issued a full iteration before their vmcnt wait.
__global__ __launch_bounds__(256) void gemm_kernel(
    const bf16* __restrict__ Wv_p,   // [9][256][512]
    const bf16* __restrict__ M_qk,   // [256][512]
    const bf16* __restrict__ ms_t,   // [B][4096][512]
    const float* __restrict__ d_qk,
    const bf16* __restrict__ zerob,
    float* __restrict__ v3, bf16* __restrict__ qk_out) {
    __shared__ __align__(16) bf16 Alds[2][128 * 32];  // [buf][c][f] 8KB each
    __shared__ __align__(16) bf16 Blds[2][128 * 32];  // [buf][p][f] 8KB each

    const int tx = threadIdx.x;
    const int wave = tx >> 6, lane = tx & 63;
    const int ptile = blockIdx.x, ctile = blockIdx.y;
    const int z = blockIdx.z;
    const int mode = (z >= 12);                 // 0=conv partial, 1=qk
    const int b = mode ? (z - 12) : (z / 3);
    const int tg = mode ? 0 : (z % 3);
    const int t0 = tg * 3;
    const int NIT = mode ? 16 : 48;             // ntaps*16 K-steps

    const bf16* Wbase = mode ? M_qk : (Wv_p + (size_t)t0 * CCh * CFh);
    const bf16* msb = ms_t + (size_t)b * PLO * CFh;

    // staging lane mapping: issue q covers bytes [wave*2048 + q*1024, +1024)
    int idx0 = wave * 2048 + lane * 16;
    int idx1 = idx0 + 1024;
    int rA0 = idx0 >> 6, fq0 = (idx0 >> 4) & 3;   // row 0..127, 16B-chunk 0..3
    int rA1 = idx1 >> 6, fq1 = (idx1 >> 4) & 3;
    const size_t aoff0 = (size_t)(ctile * 128 + rA0) * CFh + fq0 * 8;
    const size_t aoff1 = (size_t)(ctile * 128 + rA1) * CFh + fq1 * 8;

    const int p0 = ptile * 128 + rA0, p1 = ptile * 128 + rA1;
    const int i0 = p0 >> 6, j0 = p0 & 63;
    const int i1 = p1 >> 6, j1 = p1 & 63;

    f32x4 acc[4][4];
#pragma unroll
    for (int mi = 0; mi < 4; ++mi)
#pragma unroll
        for (int ni = 0; ni < 4; ++ni) acc[mi][ni] = f32x4{0.f, 0.f, 0.f, 0.f};

    const int wm = wave >> 1, wn = wave & 1;
    const int quad = lane >> 4, l15 = lane & 15;

    // per-tap source pointers (tap changes every 16 K-steps; uniform branch)
    const bf16* bsrc0; const bf16* bsrc1; const bf16* Wt;
#define SET_TAP(tt) do {                                                        \
        int t_ = (tt);                                                          \
        int dy = mode ? 0 : ((t0 + t_) / 3 - 1);                                \
        int dx = mode ? 0 : ((t0 + t_) % 3 - 1);                                \
        int si0 = i0 + dy, sj0 = j0 + dx, si1 = i1 + dy, sj1 = j1 + dx;         \
        bsrc0 = ((unsigned)si0 < 64u && (unsigned)sj0 < 64u)                    \
                    ? msb + (size_t)(si0 * 64 + sj0) * CFh + fq0 * 8 : zerob;   \
        bsrc1 = ((unsigned)si1 < 64u && (unsigned)sj1 < 64u)                    \
                    ? msb + (size_t)(si1 * 64 + sj1) * CFh + fq1 * 8 : zerob;   \
        Wt = Wbase + (size_t)t_ * CCh * CFh;                                    \
    } while (0)

    SET_TAP(0);
    {   // prologue: stage K-step 0 into buf 0
        char* lA = (char*)(&Alds[0][0]) + wave * 2048;
        char* lB = (char*)(&Blds[0][0]) + wave * 2048;
        gll16(Wt + aoff0, lA);
        gll16(Wt + aoff1, lA + 1024);
        gll16(bsrc0, lB);
        gll16(bsrc1, lB + 1024);
    }
    asm volatile("s_waitcnt vmcnt(0)" ::: "memory");
    __builtin_amdgcn_s_barrier();
    asm volatile("" ::: "memory");

    for (int it = 0; it < NIT; ++it) {
        const int buf = it & 1;
        const int nx = it + 1;
        if (nx < NIT) {
            // stage K-step nx into buf^1; its wait is one full iteration later
            if ((nx & 15) == 0) SET_TAP(nx >> 4);
            const int fo = (nx & 15) * 32;
            char* lA = (char*)(&Alds[buf ^ 1][0]) + wave * 2048;
            char* lB = (char*)(&Blds[buf ^ 1][0]) + wave * 2048;
            gll16(Wt + aoff0 + fo, lA);
            gll16(Wt + aoff1 + fo, lA + 1024);
            gll16(bsrc0 + fo, lB);
            gll16(bsrc1 + fo, lB + 1024);
            // wait only the 4 OLDEST loads (= buf's data); 4 newest stay in flight
            asm volatile("s_waitcnt vmcnt(4)" ::: "memory");
        } else {
            asm volatile("s_waitcnt vmcnt(0)" ::: "memory");
        }
        __builtin_amdgcn_s_barrier();   // all waves' buf loads landed
        asm volatile("" ::: "memory");

        const bf16* Ab = &Alds[buf][0];
        const bf16* Bb = &Blds[buf][0];
        bf16x8 af[4], bfr[4];
#pragma unroll
        for (int mi = 0; mi < 4; ++mi)
            af[mi] = *(const bf16x8*)&Ab[(wm * 64 + mi * 16 + l15) * 32 + quad * 8];
#pragma unroll
        for (int ni = 0; ni < 4; ++ni)
            bfr[ni] = *(const bf16x8*)&Bb[(wn * 64 + ni * 16 + l15) * 32 + quad * 8];
#pragma unroll
        for (int mi = 0; mi < 4; ++mi)
#pragma unroll
            for (int ni = 0; ni < 4; ++ni)
                acc[mi][ni] = __builtin_amdgcn_mfma_f32_16x16x32_bf16(
                    af[mi], bfr[ni], acc[mi][ni], 0, 0, 0);

        asm volatile("" ::: "memory");
        __builtin_amdgcn_s_barrier();   // all waves done reading buf before
        asm volatile("" ::: "memory");  // next iter's stage overwrites it
    }
#undef SET_TAP

    // C/D layout: col = lane&15 (pixel), row = quad*4 + r (channel)
    if (mode) {
        bf16* obase = qk_out + (size_t)b * CCh * PLO;
#pragma unroll
        for (int mi = 0; mi < 4; ++mi) {
            int cb = ctile * 128 + wm * 64 + mi * 16 + quad * 4;
#pragma unroll
            for (int ni = 0; ni < 4; ++ni) {
                int p = ptile * 128 + wn * 64 + ni * 16 + l15;
                bf16* op = obase + (size_t)cb * PLO + p;
#pragma unroll
                for (int r = 0; r < 4; ++r)
                    op[(size_t)r * PLO] = (bf16)(acc[mi][ni][r] + d_qk[cb + r]);
            }
        }
    } else {
        float* obase = v3 + (size_t)(tg * NB + b) * CCh * PLO;
#pragma unroll
        for (int mi = 0; mi < 4; ++mi) {
            int cb = ctile * 128 + wm * 64 + mi * 16 + quad * 4;
#pragma unroll
            for (int ni = 0; ni < 4; ++ni) {
                int p = ptile * 128 + wn * 64 + ni * 16 + l15;
                float* op = obase + (size_t)cb * PLO + p;
#pragma unroll
                for (int r = 0; r < 4; ++r)
                    op[(size_t)r * PLO] = acc[mi][ni][r];
            }
        }
    }
}

// ---------------------------------------------------------------------------
// attention, single ctx pass: block = 512 thr, 64 pixels (one 64-wide w strip).
// Thread: 4 consecutive w-pixels (f32x4 lanes) x 8 channels x 4 n held in VGPRs.
// Register-cached ctx (128 VGPR) is traffic-optimal: R4 proved re-reading ctx
// costs its full transfer time (+32us). 2 waves/SIMD is acceptable here.
__global__ __launch_bounds__(512) void attn_kernel(
    const float* __restrict__ ctx,   // [4][4][256][128][128]
    const bf16* __restrict__ qk,     // [4][256][4096]
    const float* __restrict__ v3,    // [3][4][256][4096] conv partials
    const float* __restrict__ Wv_b,  // [256]
    float* __restrict__ out) {       // [4][256][128][128]
    __shared__ f32x4 swred[4][8][16];  // [n][wave][pq]
    const int tx = threadIdx.x;
    const int pq = tx & 15;            // which 4-pixel group
    const int cc = tx >> 4;            // channel chunk 0..31
    const int lane = tx & 63;
    const int wv = tx >> 6;
    const int quad = lane >> 4;

    const int pbase = blockIdx.x << 6;
    const int b = pbase >> 14;
    const int rem = pbase & 16383;
    const int hh = rem >> 7;
    const int w0 = rem & 127;          // 0 or 64
    const int wq = w0 + pq * 4;
    const int i = hh >> 1, j0 = wq >> 1;   // j0 even

    const int c0 = cc * 8;
    const size_t NSTR = (size_t)CCh * PHI;
    const float* cbase = ctx + (size_t)b * NN * NSTR + (size_t)c0 * PHI
                             + (size_t)hh * WW + wq;
    const bf16* qkb = qk + ((size_t)b * CCh + c0) * PLO + i * 64 + j0;
    const float* vbp = v3 + ((size_t)b * CCh + c0) * PLO + i * 64 + j0;

    f32x4 vals[4][8];
    f32x4 s[4];
#pragma unroll
    for (int n = 0; n < 4; ++n) s[n] = f32x4{0.f, 0.f, 0.f, 0.f};

#pragma unroll
    for (int cj = 0; cj < 8; ++cj) {
        unsigned qw = *(const unsigned*)(qkb + (size_t)cj * PLO);
        float qa = __uint_as_float(qw << 16);
        float qb = __uint_as_float(qw & 0xffff0000u);
        f32x4 qv = {qa, qa, qb, qb};
#pragma unroll
        for (int n = 0; n < 4; ++n) {
            vals[n][cj] = *(const f32x4*)(cbase + n * NSTR + (size_t)cj * PHI);
            s[n] += vals[n][cj] * qv;
        }
    }
    // reduce over the 4 quads within each wave (cc bits 0..1 live in lane bits 4..5)
#pragma unroll
    for (int n = 0; n < 4; ++n) {
#pragma unroll
        for (int m = 16; m <= 32; m <<= 1) {
            f32x4 t;
            t[0] = __shfl_xor(s[n][0], m);
            t[1] = __shfl_xor(s[n][1], m);
            t[2] = __shfl_xor(s[n][2], m);
            t[3] = __shfl_xor(s[n][3], m);
            s[n] += t;
        }
    }
    // lane with quad q publishes n=q for its wave
    f32x4 sq = (quad == 0) ? s[0] : (quad == 1) ? s[1] : (quad == 2) ? s[2] : s[3];
    swred[quad][wv][pq] = sq;
    __syncthreads();

    f32x4 t4[4];
#pragma unroll
    for (int n = 0; n < 4; ++n) {
        f32x4 a = swred[n][0][pq];
#pragma unroll
        for (int w = 1; w < 8; ++w) a += swred[n][w][pq];
        t4[n] = a;
    }
    f32x4 mx;
#pragma unroll
    for (int k = 0; k < 4; ++k)
        mx[k] = fmaxf(fmaxf(t4[0][k], t4[1][k]), fmaxf(t4[2][k], t4[3][k]));
    f32x4 e[4];
#pragma unroll
    for (int n = 0; n < 4; ++n)
#pragma unroll
        for (int k = 0; k < 4; ++k) e[n][k] = __expf(t4[n][k] - mx[k]);
    f32x4 ssum = e[0] + e[1] + e[2] + e[3];
    f32x4 a4[4];
#pragma unroll
    for (int n = 0; n < 4; ++n)
#pragma unroll
        for (int k = 0; k < 4; ++k) a4[n][k] = e[n][k] / ssum[k];

    float* outp = out + ((size_t)b * CCh + c0) * PHI + (size_t)hh * WW + wq;
#pragma unroll
    for (int cj = 0; cj < 8; ++cj) {
        f32x2 vv = *(const f32x2*)(vbp + (size_t)cj * PLO);
        vv += *(const f32x2*)(vbp + 4194304 + (size_t)cj * PLO);
        vv += *(const f32x2*)(vbp + 8388608 + (size_t)cj * PLO);
        float bc = Wv_b[c0 + cj];
        float va = vv[0] + bc, vb2 = vv[1] + bc;
        f32x4 o = vals[0][cj] * a4[0] + vals[1][cj] * a4[1] +
                  vals[2][cj] * a4[2] + vals[3][cj] * a4[3] +
                  f32x4{va, va, vb2, vb2};
        *(f32x4*)(outp + (size_t)cj * PHI) = o;
    }
}

// ---------------------------------------------------------------------------
extern "C" void kernel_launch(void* const* d_in, const int* in_sizes, int n_in,
                              void* d_out, int out_size, void* d_ws, size_t ws_size,
                              hipStream_t stream) {
    const float* ctx  = (const float*)d_in[0];
    const float* ms   = (const float*)d_in[1];
    const float* Wc_w = (const float*)d_in[2];
    // d_in[3] = Wc_b: constant across n at each pixel -> cancels in softmax.
    const float* Wf_w = (const float*)d_in[4];
    const float* Wf_b = (const float*)d_in[5];
    const float* Wv_w = (const float*)d_in[6];
    const float* Wv_b = (const float*)d_in[7];
    float* out = (float*)d_out;

    char* ws = (char*)d_ws;
    bf16*  ms_t  = (bf16*)ws;                     // 16,777,216 B
    bf16*  Wv_p  = (bf16*)(ws + 16777216);        //  2,359,296 B
    bf16*  M_qk  = (bf16*)(ws + 19136512);        //    262,144 B
    float* d_qk  = (float*)(ws + 19398656);       //      1,024 B
    bf16*  zerob = (bf16*)(ws + 19399680);        //      2,048 B
    bf16*  qk    = (bf16*)(ws + 19401728);        //  8,388,608 B
    float* v3    = (float*)(ws + 27790336);       // 50,331,648 B (total ~78.1 MB)

    prep_mqk<<<dim3(2, 256), 256, 0, stream>>>(Wc_w, Wf_w, Wf_b, M_qk, d_qk);
    prep_ms<<<dim3(128, 16, 4), 256, 0, stream>>>(ms, ms_t);
    prep_wv<<<dim3(4608), 256, 0, stream>>>(Wv_w, Wv_p, zerob);
    gemm_kernel<<<dim3(32, 2, 16), 256, 0, stream>>>(Wv_p, M_qk, ms_t, d_qk,
                                                     zerob, v3, qk);
    attn_kernel<<<dim3(1024), 512, 0, stream>>>(ctx, qk, v3, Wv_b, out);
}

// Round 6
// 512.774 us; speedup vs baseline: 1.0433x; 1.0017x over previous
//
#include <hip/hip_runtime.h>

// Problem constants
#define NB   4      // batch
#define NN   4      // contexts per pixel
#define CCh  256    // Cc
#define CFh  512    // Cf
#define HH   128
#define WW   128
#define PLO  4096   // 64*64 low-res pixels
#define PHI  16384  // 128*128 hi-res pixels

typedef __bf16 bf16;
typedef __bf16 bf16x8 __attribute__((ext_vector_type(8)));
typedef float  f32x4  __attribute__((ext_vector_type(4)));
typedef float  f32x2  __attribute__((ext_vector_type(2)));

__device__ __forceinline__ void gll16(const void* g, void* lds) {
    __builtin_amdgcn_global_load_lds(
        (const __attribute__((address_space(1))) void*)g,
        (__attribute__((address_space(3))) void*)lds, 16, 0, 0);
}

__device__ __forceinline__ unsigned pack2bf(float a, float b) {
    unsigned short ua = __builtin_bit_cast(unsigned short, (bf16)a);
    unsigned short ub = __builtin_bit_cast(unsigned short, (bf16)b);
    return (unsigned)ua | ((unsigned)ub << 16);
}

// ---------------------------------------------------------------------------
// prep 1: M_qk[c][f] = sum_o Wc_w[o][c] * Wf_w[o][f]  (bf16 out)
//         d_qk[c]    = sum_o Wc_w[o][c] * Wf_b[o]     (fp32, parallel reduce)
__global__ void prep_mqk(const float* __restrict__ Wc_w, const float* __restrict__ Wf_w,
                         const float* __restrict__ Wf_b, bf16* __restrict__ M_qk,
                         float* __restrict__ d_qk) {
    __shared__ float red[256];
    int c = blockIdx.y;
    int f = blockIdx.x * 256 + threadIdx.x;
    float s = 0.f;
#pragma unroll 8
    for (int o = 0; o < CCh; ++o)
        s += Wc_w[o * CCh + c] * Wf_w[o * CFh + f];
    M_qk[c * CFh + f] = (bf16)s;
    if (blockIdx.x == 0) {          // block-uniform branch: barriers are safe
        int o = threadIdx.x;
        red[o] = Wc_w[o * CCh + c] * Wf_b[o];
        __syncthreads();
        for (int st = 128; st > 0; st >>= 1) {
            if (threadIdx.x < st) red[threadIdx.x] += red[threadIdx.x + st];
            __syncthreads();
        }
        if (threadIdx.x == 0) d_qk[c] = red[0];
    }
}

// ---------------------------------------------------------------------------
// prep 2: transpose mainstream [B][512][4096] fp32 -> ms_t [B][4096][512] bf16
// Write phase packs 2 bf16 per u32 store (halves store instrs vs scalar bf16).
__global__ void prep_ms(const float* __restrict__ ms, bf16* __restrict__ ms_t) {
    __shared__ float tile[32][33];   // [f_local][p_local]
    int b = blockIdx.z;
    int p0 = blockIdx.x * 32, f0 = blockIdx.y * 32;
    int tx = threadIdx.x;
    int r = tx >> 5, cc = tx & 31;
    const float* src = ms + (size_t)b * CFh * PLO;
#pragma unroll
    for (int q = 0; q < 4; ++q) {
        int fl = q * 8 + r;
        tile[fl][cc] = src[(size_t)(f0 + fl) * PLO + p0 + cc];
    }
    __syncthreads();
    bf16* dst = ms_t + (size_t)b * PLO * CFh;
    int fp = tx & 15;                // f-pair index: f_local = 2*fp, 2*fp+1
    int r2 = tx >> 4;                // 0..15
#pragma unroll
    for (int q = 0; q < 2; ++q) {
        int pl = q * 16 + r2;        // p_local 0..31
        unsigned w = pack2bf(tile[2 * fp][pl], tile[2 * fp + 1][pl]);
        *((unsigned*)(dst + (size_t)(p0 + pl) * CFh + f0) + fp) = w;
    }
}

// ---------------------------------------------------------------------------
// prep 3: pack Wv_w [256][512][3][3] fp32 -> Wv_p [9][256][512] bf16; zero zerobuf
__global__ void prep_wv(const float* __restrict__ Wv_w, bf16* __restrict__ Wv_p,
                        bf16* __restrict__ zerob) {
    int tid = blockIdx.x * 256 + threadIdx.x;   // t-major: (t*256 + c)*512 + f
    int t = tid / (CCh * CFh);
    int rem = tid % (CCh * CFh);
    int c = rem / CFh, f = rem % CFh;
    Wv_p[tid] = (bf16)Wv_w[(size_t)(c * CFh + f) * 9 + t];
    if (tid < 1024) zerob[tid] = (bf16)0.f;
}

// ---------------------------------------------------------------------------
// GEMM: M=channels(128-tile), N=pixels(128-tile), BK=32, 256 thr = 4 waves.
// grid (32, 2, 16): z<12 -> conv tap-group tg=z%3, b=z/3, taps [3tg,3tg+3),
//   writes fp32 partials (no bias) to v3[tg][b][256][4096].
// z>=12 -> qk (1 tap), b=z-12, writes bf16 (+d_qk bias) to qk_out.
// (R0/R3-proven m97-class structure: serial stage, compiler-scheduled,
//  4 blocks/CU. R5's counted-vmcnt pipeline regressed +10us -> reverted.)
__global__ __launch_bounds__(256) void gemm_kernel(
    const bf16* __restrict__ Wv_p,   // [9][256][512]
    const bf16* __restrict__ M_qk,   // [256][512]
    const bf16* __restrict__ ms_t,   // [B][4096][512]
    const float* __restrict__ d_qk,
    const bf16* __restrict__ zerob,
    float* __restrict__ v3, bf16* __restrict__ qk_out) {
    __shared__ __align__(16) bf16 Alds[128 * 32];  // [c][f]
    __shared__ __align__(16) bf16 Blds[128 * 32];  // [p][f]

    const int tx = threadIdx.x;
    const int wave = tx >> 6, lane = tx & 63;
    const int ptile = blockIdx.x, ctile = blockIdx.y;
    const int z = blockIdx.z;
    const int mode = (z >= 12);                 // 0=conv partial, 1=qk
    const int b = mode ? (z - 12) : (z / 3);
    const int tg = mode ? 0 : (z % 3);
    const int t0 = tg * 3;
    const int ntaps = mode ? 1 : 3;

    const bf16* Wbase = mode ? M_qk : (Wv_p + (size_t)t0 * CCh * CFh);
    const bf16* msb = ms_t + (size_t)b * PLO * CFh;

    // staging lane mapping: issue q covers bytes [wave*2048 + q*1024, +1024)
    int idx0 = wave * 2048 + lane * 16;
    int idx1 = idx0 + 1024;
    int rA0 = idx0 >> 6, fq0 = (idx0 >> 4) & 3;   // row 0..127, 16B-chunk 0..3
    int rA1 = idx1 >> 6, fq1 = (idx1 >> 4) & 3;
    const size_t aoff0 = (size_t)(ctile * 128 + rA0) * CFh + fq0 * 8;
    const size_t aoff1 = (size_t)(ctile * 128 + rA1) * CFh + fq1 * 8;
    char* ldsA0 = (char*)Alds + wave * 2048;
    char* ldsA1 = ldsA0 + 1024;
    char* ldsB0 = (char*)Blds + wave * 2048;
    char* ldsB1 = ldsB0 + 1024;

    const int p0 = ptile * 128 + rA0, p1 = ptile * 128 + rA1;
    const int i0 = p0 >> 6, j0 = p0 & 63;
    const int i1 = p1 >> 6, j1 = p1 & 63;

    f32x4 acc[4][4];
#pragma unroll
    for (int mi = 0; mi < 4; ++mi)
#pragma unroll
        for (int ni = 0; ni < 4; ++ni) acc[mi][ni] = f32x4{0.f, 0.f, 0.f, 0.f};

    const int wm = wave >> 1, wn = wave & 1;
    const int quad = lane >> 4, l15 = lane & 15;

    for (int t = 0; t < ntaps; ++t) {
        const int dy = mode ? 0 : ((t0 + t) / 3 - 1);
        const int dx = mode ? 0 : ((t0 + t) % 3 - 1);
        const bf16* Wt = Wbase + (size_t)t * CCh * CFh;
        int si0 = i0 + dy, sj0 = j0 + dx, si1 = i1 + dy, sj1 = j1 + dx;
        bool ok0 = (unsigned)si0 < 64u && (unsigned)sj0 < 64u;
        bool ok1 = (unsigned)si1 < 64u && (unsigned)sj1 < 64u;
        const bf16* bsrc0 = ok0 ? msb + (size_t)(si0 * 64 + sj0) * CFh + fq0 * 8 : zerob;
        const bf16* bsrc1 = ok1 ? msb + (size_t)(si1 * 64 + sj1) * CFh + fq1 * 8 : zerob;

        for (int fc = 0; fc < CFh / 32; ++fc) {
            const int f0 = fc * 32;
            __syncthreads();   // prev compute done before overwriting LDS
            gll16(Wt + aoff0 + f0, ldsA0);
            gll16(Wt + aoff1 + f0, ldsA1);
            gll16(bsrc0 + f0, ldsB0);
            gll16(bsrc1 + f0, ldsB1);
            __syncthreads();

            bf16x8 af[4], bfr[4];
#pragma unroll
            for (int mi = 0; mi < 4; ++mi)
                af[mi] = *(const bf16x8*)&Alds[(wm * 64 + mi * 16 + l15) * 32 + quad * 8];
#pragma unroll
            for (int ni = 0; ni < 4; ++ni)
                bfr[ni] = *(const bf16x8*)&Blds[(wn * 64 + ni * 16 + l15) * 32 + quad * 8];
#pragma unroll
            for (int mi = 0; mi < 4; ++mi)
#pragma unroll
                for (int ni = 0; ni < 4; ++ni)
                    acc[mi][ni] = __builtin_amdgcn_mfma_f32_16x16x32_bf16(
                        af[mi], bfr[ni], acc[mi][ni], 0, 0, 0);
        }
    }

    // C/D layout: col = lane&15 (pixel), row = quad*4 + r (channel)
    if (mode) {
        bf16* obase = qk_out + (size_t)b * CCh * PLO;
#pragma unroll
        for (int mi = 0; mi < 4; ++mi) {
            int cb = ctile * 128 + wm * 64 + mi * 16 + quad * 4;
#pragma unroll
            for (int ni = 0; ni < 4; ++ni) {
                int p = ptile * 128 + wn * 64 + ni * 16 + l15;
                bf16* op = obase + (size_t)cb * PLO + p;
#pragma unroll
                for (int r = 0; r < 4; ++r)
                    op[(size_t)r * PLO] = (bf16)(acc[mi][ni][r] + d_qk[cb + r]);
            }
        }
    } else {
        float* obase = v3 + (size_t)(tg * NB + b) * CCh * PLO;
#pragma unroll
        for (int mi = 0; mi < 4; ++mi) {
            int cb = ctile * 128 + wm * 64 + mi * 16 + quad * 4;
#pragma unroll
            for (int ni = 0; ni < 4; ++ni) {
                int p = ptile * 128 + wn * 64 + ni * 16 + l15;
                float* op = obase + (size_t)cb * PLO + p;
#pragma unroll
                for (int r = 0; r < 4; ++r)
                    op[(size_t)r * PLO] = acc[mi][ni][r];
            }
        }
    }
}

// ---------------------------------------------------------------------------
// attention: block = 256 thr, 32 pixels (one 32-wide w strip). 2048 blocks.
// Per-thread structure IDENTICAL to the proven R3 kernel (8 ch x 4 px x 4 n,
// f32x4 vals cache = traffic-optimal, R4 proved re-reading ctx costs +32us).
// Change: block 512->256 thr. At ~200 VGPR (2 waves/SIMD) a 4-wave block
// gives 2 resident blocks/CU (vs 1 for 8-wave), so one block's BW phase
// overlaps the other's reduce/softmax/epilogue across the barrier.
__global__ __launch_bounds__(256) void attn_kernel(
    const float* __restrict__ ctx,   // [4][4][256][128][128]
    const bf16* __restrict__ qk,     // [4][256][4096]
    const float* __restrict__ v3,    // [3][4][256][4096] conv partials
    const float* __restrict__ Wv_b,  // [256]
    float* __restrict__ out) {       // [4][256][128][128]
    __shared__ f32x4 swred[4][4][8];   // [n][wave][pq]  2KB
    const int tx = threadIdx.x;
    const int pq = tx & 7;             // which 4-pixel group (0..7)
    const int cc = tx >> 3;            // channel chunk 0..31 (8 ch each)
    const int lane = tx & 63;
    const int wv = tx >> 6;            // 0..3
    const int g = lane >> 3;           // cc-low group 0..7 within wave

    const int pbase = blockIdx.x << 5;     // 32 px per block
    const int b = pbase >> 14;
    const int rem = pbase & 16383;
    const int hh = rem >> 7;
    const int w0 = rem & 127;              // 0,32,64,96
    const int wq = w0 + pq * 4;
    const int i = hh >> 1, j0 = wq >> 1;   // j0 even

    const int c0 = cc * 8;
    const size_t NSTR = (size_t)CCh * PHI;
    const float* cbase = ctx + (size_t)b * NN * NSTR + (size_t)c0 * PHI
                             + (size_t)hh * WW + wq;
    const bf16* qkb = qk + ((size_t)b * CCh + c0) * PLO + i * 64 + j0;
    const float* vbp = v3 + ((size_t)b * CCh + c0) * PLO + i * 64 + j0;

    f32x4 vals[4][8];
    f32x4 s[4];
#pragma unroll
    for (int n = 0; n < 4; ++n) s[n] = f32x4{0.f, 0.f, 0.f, 0.f};

#pragma unroll
    for (int cj = 0; cj < 8; ++cj) {
        unsigned qw = *(const unsigned*)(qkb + (size_t)cj * PLO);
        float qa = __uint_as_float(qw << 16);
        float qb = __uint_as_float(qw & 0xffff0000u);
        f32x4 qv = {qa, qa, qb, qb};
#pragma unroll
        for (int n = 0; n < 4; ++n) {
            vals[n][cj] = *(const f32x4*)(cbase + n * NSTR + (size_t)cj * PHI);
            s[n] += vals[n][cj] * qv;
        }
    }
    // in-wave butterfly over cc bits 0..2 (lane bits 3..5): sums 8 cc chunks
#pragma unroll
    for (int n = 0; n < 4; ++n) {
#pragma unroll
        for (int m = 8; m <= 32; m <<= 1) {
            f32x4 t;
            t[0] = __shfl_xor(s[n][0], m);
            t[1] = __shfl_xor(s[n][1], m);
            t[2] = __shfl_xor(s[n][2], m);
            t[3] = __shfl_xor(s[n][3], m);
            s[n] += t;
        }
    }
    // groups 0..3 publish n=g for this wave (all groups hold identical sums)
    f32x4 sq = (g == 0 || g == 4) ? s[0] : (g == 1 || g == 5) ? s[1]
             : (g == 2 || g == 6) ? s[2] : s[3];
    if (g < 4) swred[g][wv][pq] = sq;
    __syncthreads();

    f32x4 t4[4];
#pragma unroll
    for (int n = 0; n < 4; ++n) {
        f32x4 a = swred[n][0][pq];
#pragma unroll
        for (int w = 1; w < 4; ++w) a += swred[n][w][pq];
        t4[n] = a;
    }
    f32x4 mx;
#pragma unroll
    for (int k = 0; k < 4; ++k)
        mx[k] = fmaxf(fmaxf(t4[0][k], t4[1][k]), fmaxf(t4[2][k], t4[3][k]));
    f32x4 e[4];
#pragma unroll
    for (int n = 0; n < 4; ++n)
#pragma unroll
        for (int k = 0; k < 4; ++k) e[n][k] = __expf(t4[n][k] - mx[k]);
    f32x4 ssum = e[0] + e[1] + e[2] + e[3];
    f32x4 a4[4];
#pragma unroll
    for (int n = 0; n < 4; ++n)
#pragma unroll
        for (int k = 0; k < 4; ++k) a4[n][k] = e[n][k] / ssum[k];

    float* outp = out + ((size_t)b * CCh + c0) * PHI + (size_t)hh * WW + wq;
#pragma unroll
    for (int cj = 0; cj < 8; ++cj) {
        f32x2 vv = *(const f32x2*)(vbp + (size_t)cj * PLO);
        vv += *(const f32x2*)(vbp + 4194304 + (size_t)cj * PLO);
        vv += *(const f32x2*)(vbp + 8388608 + (size_t)cj * PLO);
        float bc = Wv_b[c0 + cj];
        float va = vv[0] + bc, vb2 = vv[1] + bc;
        f32x4 o = vals[0][cj] * a4[0] + vals[1][cj] * a4[1] +
                  vals[2][cj] * a4[2] + vals[3][cj] * a4[3] +
                  f32x4{va, va, vb2, vb2};
        *(f32x4*)(outp + (size_t)cj * PHI) = o;
    }
}

// ---------------------------------------------------------------------------
extern "C" void kernel_launch(void* const* d_in, const int* in_sizes, int n_in,
                              void* d_out, int out_size, void* d_ws, size_t ws_size,
                              hipStream_t stream) {
    const float* ctx  = (const float*)d_in[0];
    const float* ms   = (const float*)d_in[1];
    const float* Wc_w = (const float*)d_in[2];
    // d_in[3] = Wc_b: constant across n at each pixel -> cancels in softmax.
    const float* Wf_w = (const float*)d_in[4];
    const float* Wf_b = (const float*)d_in[5];
    const float* Wv_w = (const float*)d_in[6];
    const float* Wv_b = (const float*)d_in[7];
    float* out = (float*)d_out;

    char* ws = (char*)d_ws;
    bf16*  ms_t  = (bf16*)ws;                     // 16,777,216 B
    bf16*  Wv_p  = (bf16*)(ws + 16777216);        //  2,359,296 B
    bf16*  M_qk  = (bf16*)(ws + 19136512);        //    262,144 B
    float* d_qk  = (float*)(ws + 19398656);       //      1,024 B
    bf16*  zerob = (bf16*)(ws + 19399680);        //      2,048 B
    bf16*  qk    = (bf16*)(ws + 19401728);        //  8,388,608 B
    float* v3    = (float*)(ws + 27790336);       // 50,331,648 B (total ~78.1 MB)

    prep_mqk<<<dim3(2, 256), 256, 0, stream>>>(Wc_w, Wf_w, Wf_b, M_qk, d_qk);
    prep_ms<<<dim3(128, 16, 4), 256, 0, stream>>>(ms, ms_t);
    prep_wv<<<dim3(4608), 256, 0, stream>>>(Wv_w, Wv_p, zerob);
    gemm_kernel<<<dim3(32, 2, 16), 256, 0, stream>>>(Wv_p, M_qk, ms_t, d_qk,
                                                     zerob, v3, qk);
    attn_kernel<<<dim3(2048), 256, 0, stream>>>(ctx, qk, v3, Wv_b, out);
}

// Round 7
// 491.535 us; speedup vs baseline: 1.0883x; 1.0432x over previous
//
#include <hip/hip_runtime.h>

// Problem constants
#define NB   4      // batch
#define NN   4      // contexts per pixel
#define CCh  256    // Cc
#define CFh  512    // Cf
#define HH   128
#define WW   128
#define PLO  4096   // 64*64 low-res pixels
#define PHI  16384  // 128*128 hi-res pixels
#define GR   66     // guarded lo-res rows  (1 + 64 + 1)
#define GC   72     // guarded lo-res col stride (1 + 64 + 1 + pad to 72)
#define PLANE_E (GR * GC * CFh)   // elements per guarded ms plane (2,433,024)

typedef __bf16 bf16;
typedef __bf16 bf16x8 __attribute__((ext_vector_type(8)));
typedef float  f32x4  __attribute__((ext_vector_type(4)));
typedef float  f32x2  __attribute__((ext_vector_type(2)));

__device__ __forceinline__ void gll16(const void* g, void* lds) {
    __builtin_amdgcn_global_load_lds(
        (const __attribute__((address_space(1))) void*)g,
        (__attribute__((address_space(3))) void*)lds, 16, 0, 0);
}

__device__ __forceinline__ unsigned pack2bf(float a, float b) {
    unsigned short ua = __builtin_bit_cast(unsigned short, (bf16)a);
    unsigned short ub = __builtin_bit_cast(unsigned short, (bf16)b);
    return (unsigned)ua | ((unsigned)ub << 16);
}

// ---------------------------------------------------------------------------
// fused prep (block-range dispatch):
//  blocks [0,512):      M_qk[c][f] = sum_o Wc_w[o][c]*Wf_w[o][f]; d_qk reduce
//  blocks [512,5120):   pack Wv_w [256][512][3][3] -> Wv_p [9][256][512] bf16
//  blocks [5120,13312): transpose ms [B][512][4096] -> guarded msg
//                       [B][66][72][512] bf16 (interior rows 1..64, cols 1..64;
//                       guards pre-zeroed by hipMemsetAsync)
__global__ void prep_fused(const float* __restrict__ Wc_w, const float* __restrict__ Wf_w,
                           const float* __restrict__ Wf_b, const float* __restrict__ ms,
                           const float* __restrict__ Wv_w,
                           bf16* __restrict__ M_qk, float* __restrict__ d_qk,
                           bf16* __restrict__ msg, bf16* __restrict__ Wv_p) {
    __shared__ float red[256];
    __shared__ float tile[32][33];
    const int bid = blockIdx.x, tx = threadIdx.x;

    if (bid < 512) {
        // ---- M_qk + d_qk ----
        int c = bid >> 1;
        int f = (bid & 1) * 256 + tx;
        float s = 0.f;
#pragma unroll 8
        for (int o = 0; o < CCh; ++o)
            s += Wc_w[o * CCh + c] * Wf_w[o * CFh + f];
        M_qk[c * CFh + f] = (bf16)s;
        if ((bid & 1) == 0) {       // block-uniform: barriers safe
            red[tx] = Wc_w[tx * CCh + c] * Wf_b[tx];
            __syncthreads();
            for (int st = 128; st > 0; st >>= 1) {
                if (tx < st) red[tx] += red[tx + st];
                __syncthreads();
            }
            if (tx == 0) d_qk[c] = red[0];
        }
    } else if (bid < 5120) {
        // ---- Wv pack ----
        int tid = (bid - 512) * 256 + tx;   // (t*256 + c)*512 + f
        int t = tid / (CCh * CFh);
        int rem = tid % (CCh * CFh);
        int c = rem / CFh, f = rem % CFh;
        Wv_p[tid] = (bf16)Wv_w[(size_t)(c * CFh + f) * 9 + t];
    } else {
        // ---- ms transpose into guarded plane ----
        int id2 = bid - 5120;
        int x = id2 & 127, y = (id2 >> 7) & 15, b = id2 >> 11;
        int p0 = x * 32, f0 = y * 32;
        int r = tx >> 5, cc = tx & 31;
        const float* src = ms + (size_t)b * CFh * PLO;
#pragma unroll
        for (int q = 0; q < 4; ++q) {
            int fl = q * 8 + r;
            tile[fl][cc] = src[(size_t)(f0 + fl) * PLO + p0 + cc];
        }
        __syncthreads();
        bf16* dstb = msg + (size_t)b * PLANE_E;
        int fp = tx & 15, r2 = tx >> 4;
#pragma unroll
        for (int q = 0; q < 2; ++q) {
            int pl = q * 16 + r2;            // p_local 0..31 (stays in one row)
            int pix = p0 + pl;
            int pi = pix >> 6, pj = pix & 63;
            unsigned w = pack2bf(tile[2 * fp][pl], tile[2 * fp + 1][pl]);
            *((unsigned*)(dstb + ((size_t)(pi + 1) * GC + pj + 1) * CFh + f0) + fp) = w;
        }
    }
}

// ---------------------------------------------------------------------------
// GEMM: M=channels(128-tile), N=pixels(128-tile), BK=32, 256 thr = 4 waves.
// grid (32, 2, 16): z<12 -> conv tap-group tg=z%3, b=z/3. Tap-group has FIXED
//   dy=tg-1, dx in {-1,0,1}: ONE widened B-tile [2 rows][72 cols][32f] serves
//   all 3 taps per K-step -> conv barrier-pairs 48->16, B-staging -62%.
// z>=12 -> qk (1 tap), b=z-12, writes bf16 (+d_qk bias) to qk_out.
// msg is 2D-guarded (zero borders) -> staging has NO masks/selects.
// Serial 2-barrier protocol per K-step (R0/R3-proven; pipelining regressed).
__global__ __launch_bounds__(256) void gemm_kernel(
    const bf16* __restrict__ Wv_p,   // [9][256][512]
    const bf16* __restrict__ M_qk,   // [256][512]
    const bf16* __restrict__ msg,    // [B][66][72][512] guarded
    const float* __restrict__ d_qk,
    float* __restrict__ v3, bf16* __restrict__ qk_out) {
    __shared__ __align__(16) bf16 Alds[3 * 128 * 32];   // [tap][c][32f] 24KB
    __shared__ __align__(16) bf16 Blds[2 * GC * 32];    // [ri][jj][32f] 9216B

    const int tx = threadIdx.x;
    const int wave = tx >> 6, lane = tx & 63;
    const int ptile = blockIdx.x, ctile = blockIdx.y;
    const int z = blockIdx.z;
    const int mode = (z >= 12);                 // 0=conv partial, 1=qk
    const int b = mode ? (z - 12) : (z / 3);
    const int tg = mode ? 0 : (z % 3);
    const int dy = mode ? 0 : (tg - 1);
    const int ntaps = mode ? 1 : 3;

    const bf16* Wbase = mode ? M_qk : (Wv_p + (size_t)tg * 3 * CCh * CFh);
    const bf16* msb = msg + (size_t)b * PLANE_E;
    const int i0 = ptile * 2;                   // first lo-res row of this ptile

    // Per-issue invariant element offsets (add f0 at issue time).
    // A: issue q covers rows [s*16, s*16+16) of tap t=q>>3, s=q&7;
    //    lane L -> row s*16 + (L>>2), 8-elem chunk L&3. Dest = Alds + q*1024.
    int aoffs[6];
#pragma unroll
    for (int k = 0; k < 6; ++k) {
        int q = wave + 4 * k;
        int tap = q >> 3, s = q & 7;
        aoffs[k] = tap * (CCh * CFh) + (ctile * 128 + s * 16 + (lane >> 2)) * CFh
                 + (lane & 3) * 8;
    }
    // B: 9 issues cover flat cols cfl 0..143 of [2][72] (64B per col);
    //    lane L -> cfl = q*16 + (L>>2), chunk L&3. Dest = Blds + q*1024.
    //    LDS col jj holds image col jd = jj-1 -> msg col index = jj directly.
    int boffs[3];
#pragma unroll
    for (int k = 0; k < 3; ++k) {
        int q = wave + 4 * k;
        int cfl = q * 16 + (lane >> 2);
        int ri = (cfl >= GC) ? 1 : 0;
        int jj = cfl - GC * ri;
        boffs[k] = ((i0 + ri + dy + 1) * GC + jj) * CFh + (lane & 3) * 8;
    }

    f32x4 acc[4][4];
#pragma unroll
    for (int mi = 0; mi < 4; ++mi)
#pragma unroll
        for (int ni = 0; ni < 4; ++ni) acc[mi][ni] = f32x4{0.f, 0.f, 0.f, 0.f};

    const int wm = wave >> 1, wn = wave & 1;
    const int quad = lane >> 4, l15 = lane & 15;
    const int nA = ntaps * 2;                   // A issues per wave

    for (int fc = 0; fc < 16; ++fc) {
        const int f0 = fc * 32;
        __syncthreads();   // prev compute done before overwriting LDS
#pragma unroll
        for (int k = 0; k < 6; ++k)
            if (k < nA)
                gll16(Wbase + aoffs[k] + f0, (char*)Alds + (wave + 4 * k) * 1024);
#pragma unroll
        for (int k = 0; k < 3; ++k)
            if (wave + 4 * k < 9)
                gll16(msb + boffs[k] + f0, (char*)Blds + (wave + 4 * k) * 1024);
        __syncthreads();   // staging drained (vmcnt 0 at barrier)

        for (int t = 0; t < ntaps; ++t) {
            const int dxo = mode ? 1 : t;       // jj = j + 1 + dx = j + t (conv)
            bf16x8 af[4], bfr[4];
#pragma unroll
            for (int mi = 0; mi < 4; ++mi)
                af[mi] = *(const bf16x8*)((const char*)Alds + t * 8192 +
                          (wm * 64 + mi * 16 + l15) * 64 + quad * 16);
#pragma unroll
            for (int ni = 0; ni < 4; ++ni) {
                int pl = wn * 64 + ni * 16 + l15;
                int ri = pl >> 6, j = pl & 63;
                bfr[ni] = *(const bf16x8*)((const char*)Blds +
                           (ri * GC + j + dxo) * 64 + quad * 16);
            }
#pragma unroll
            for (int mi = 0; mi < 4; ++mi)
#pragma unroll
                for (int ni = 0; ni < 4; ++ni)
                    acc[mi][ni] = __builtin_amdgcn_mfma_f32_16x16x32_bf16(
                        af[mi], bfr[ni], acc[mi][ni], 0, 0, 0);
        }
    }

    // C/D layout: col = lane&15 (pixel), row = quad*4 + r (channel)
    if (mode) {
        bf16* obase = qk_out + (size_t)b * CCh * PLO;
#pragma unroll
        for (int mi = 0; mi < 4; ++mi) {
            int cb = ctile * 128 + wm * 64 + mi * 16 + quad * 4;
#pragma unroll
            for (int ni = 0; ni < 4; ++ni) {
                int p = ptile * 128 + wn * 64 + ni * 16 + l15;
                bf16* op = obase + (size_t)cb * PLO + p;
#pragma unroll
                for (int r = 0; r < 4; ++r)
                    op[(size_t)r * PLO] = (bf16)(acc[mi][ni][r] + d_qk[cb + r]);
            }
        }
    } else {
        float* obase = v3 + (size_t)(tg * NB + b) * CCh * PLO;
#pragma unroll
        for (int mi = 0; mi < 4; ++mi) {
            int cb = ctile * 128 + wm * 64 + mi * 16 + quad * 4;
#pragma unroll
            for (int ni = 0; ni < 4; ++ni) {
                int p = ptile * 128 + wn * 64 + ni * 16 + l15;
                float* op = obase + (size_t)cb * PLO + p;
#pragma unroll
                for (int r = 0; r < 4; ++r)
                    op[(size_t)r * PLO] = acc[mi][ni][r];
            }
        }
    }
}

// ---------------------------------------------------------------------------
// attention (R3-proven, byte-identical): block = 512 thr, 64 px strip.
// 8 ch x 4 px x 4 n per thread; 128-VGPR ctx cache = traffic-optimal (R4).
__global__ __launch_bounds__(512) void attn_kernel(
    const float* __restrict__ ctx,   // [4][4][256][128][128]
    const bf16* __restrict__ qk,     // [4][256][4096]
    const float* __restrict__ v3,    // [3][4][256][4096] conv partials
    const float* __restrict__ Wv_b,  // [256]
    float* __restrict__ out) {       // [4][256][128][128]
    __shared__ f32x4 swred[4][8][16];  // [n][wave][pq]
    const int tx = threadIdx.x;
    const int pq = tx & 15;            // which 4-pixel group
    const int cc = tx >> 4;            // channel chunk 0..31
    const int lane = tx & 63;
    const int wv = tx >> 6;
    const int quad = lane >> 4;

    const int pbase = blockIdx.x << 6;
    const int b = pbase >> 14;
    const int rem = pbase & 16383;
    const int hh = rem >> 7;
    const int w0 = rem & 127;          // 0 or 64
    const int wq = w0 + pq * 4;
    const int i = hh >> 1, j0 = wq >> 1;   // j0 even

    const int c0 = cc * 8;
    const size_t NSTR = (size_t)CCh * PHI;
    const float* cbase = ctx + (size_t)b * NN * NSTR + (size_t)c0 * PHI
                             + (size_t)hh * WW + wq;
    const bf16* qkb = qk + ((size_t)b * CCh + c0) * PLO + i * 64 + j0;
    const float* vbp = v3 + ((size_t)b * CCh + c0) * PLO + i * 64 + j0;

    f32x4 vals[4][8];
    f32x4 s[4];
#pragma unroll
    for (int n = 0; n < 4; ++n) s[n] = f32x4{0.f, 0.f, 0.f, 0.f};

#pragma unroll
    for (int cj = 0; cj < 8; ++cj) {
        unsigned qw = *(const unsigned*)(qkb + (size_t)cj * PLO);
        float qa = __uint_as_float(qw << 16);
        float qb = __uint_as_float(qw & 0xffff0000u);
        f32x4 qv = {qa, qa, qb, qb};
#pragma unroll
        for (int n = 0; n < 4; ++n) {
            vals[n][cj] = *(const f32x4*)(cbase + n * NSTR + (size_t)cj * PHI);
            s[n] += vals[n][cj] * qv;
        }
    }
    // reduce over the 4 quads within each wave (cc bits 0..1 live in lane bits 4..5)
#pragma unroll
    for (int n = 0; n < 4; ++n) {
#pragma unroll
        for (int m = 16; m <= 32; m <<= 1) {
            f32x4 t;
            t[0] = __shfl_xor(s[n][0], m);
            t[1] = __shfl_xor(s[n][1], m);
            t[2] = __shfl_xor(s[n][2], m);
            t[3] = __shfl_xor(s[n][3], m);
            s[n] += t;
        }
    }
    // lane with quad q publishes n=q for its wave
    f32x4 sq = (quad == 0) ? s[0] : (quad == 1) ? s[1] : (quad == 2) ? s[2] : s[3];
    swred[quad][wv][pq] = sq;
    __syncthreads();

    f32x4 t4[4];
#pragma unroll
    for (int n = 0; n < 4; ++n) {
        f32x4 a = swred[n][0][pq];
#pragma unroll
        for (int w = 1; w < 8; ++w) a += swred[n][w][pq];
        t4[n] = a;
    }
    f32x4 mx;
#pragma unroll
    for (int k = 0; k < 4; ++k)
        mx[k] = fmaxf(fmaxf(t4[0][k], t4[1][k]), fmaxf(t4[2][k], t4[3][k]));
    f32x4 e[4];
#pragma unroll
    for (int n = 0; n < 4; ++n)
#pragma unroll
        for (int k = 0; k < 4; ++k) e[n][k] = __expf(t4[n][k] - mx[k]);
    f32x4 ssum = e[0] + e[1] + e[2] + e[3];
    f32x4 a4[4];
#pragma unroll
    for (int n = 0; n < 4; ++n)
#pragma unroll
        for (int k = 0; k < 4; ++k) a4[n][k] = e[n][k] / ssum[k];

    float* outp = out + ((size_t)b * CCh + c0) * PHI + (size_t)hh * WW + wq;
#pragma unroll
    for (int cj = 0; cj < 8; ++cj) {
        f32x2 vv = *(const f32x2*)(vbp + (size_t)cj * PLO);
        vv += *(const f32x2*)(vbp + 4194304 + (size_t)cj * PLO);
        vv += *(const f32x2*)(vbp + 8388608 + (size_t)cj * PLO);
        float bc = Wv_b[c0 + cj];
        float va = vv[0] + bc, vb2 = vv[1] + bc;
        f32x4 o = vals[0][cj] * a4[0] + vals[1][cj] * a4[1] +
                  vals[2][cj] * a4[2] + vals[3][cj] * a4[3] +
                  f32x4{va, va, vb2, vb2};
        *(f32x4*)(outp + (size_t)cj * PHI) = o;
    }
}

// ---------------------------------------------------------------------------
extern "C" void kernel_launch(void* const* d_in, const int* in_sizes, int n_in,
                              void* d_out, int out_size, void* d_ws, size_t ws_size,
                              hipStream_t stream) {
    const float* ctx  = (const float*)d_in[0];
    const float* ms   = (const float*)d_in[1];
    const float* Wc_w = (const float*)d_in[2];
    // d_in[3] = Wc_b: constant across n at each pixel -> cancels in softmax.
    const float* Wf_w = (const float*)d_in[4];
    const float* Wf_b = (const float*)d_in[5];
    const float* Wv_w = (const float*)d_in[6];
    const float* Wv_b = (const float*)d_in[7];
    float* out = (float*)d_out;

    char* ws = (char*)d_ws;
    bf16*  msg  = (bf16*)ws;                      // 19,464,192 B (guarded ms)
    bf16*  Wv_p = (bf16*)(ws + 19464192);         //  2,359,296 B
    bf16*  M_qk = (bf16*)(ws + 21823488);         //    262,144 B
    float* d_qk = (float*)(ws + 22085632);        //      1,024 B
    bf16*  qk   = (bf16*)(ws + 22086656);         //  8,388,608 B
    float* v3   = (float*)(ws + 30475264);        // 50,331,648 B (total ~80.8 MB)

    hipMemsetAsync(msg, 0, 19464192, stream);     // zero guards (interior overwritten)
    prep_fused<<<dim3(13312), 256, 0, stream>>>(Wc_w, Wf_w, Wf_b, ms, Wv_w,
                                                M_qk, d_qk, msg, Wv_p);
    gemm_kernel<<<dim3(32, 2, 16), 256, 0, stream>>>(Wv_p, M_qk, msg, d_qk, v3, qk);
    attn_kernel<<<dim3(1024), 512, 0, stream>>>(ctx, qk, v3, Wv_b, out);
}